// Round 1
// baseline (1760.951 us; speedup 1.0000x reference)
//
#include <hip/hip_runtime.h>
#include <hip/hip_bf16.h>

typedef __hip_bfloat16 bf16;
typedef __attribute__((ext_vector_type(8))) short short8;
typedef __attribute__((ext_vector_type(4))) float float4v;

#define BM 128
#define BK 32

__device__ __forceinline__ void gload16(const bf16* g, bf16* s) {
    __builtin_amdgcn_global_load_lds(
        (const __attribute__((address_space(1))) void*)g,
        (__attribute__((address_space(3))) void*)s, 16, 0, 0);
}

// ---------------- small utility kernels ----------------

__global__ void k_zero_cnt(int* cnt) {
    if (threadIdx.x < 16) cnt[threadIdx.x] = 0;
}

__global__ void k_convert_x(const float* __restrict__ in, bf16* __restrict__ out, int n) {
    int i = (blockIdx.x * blockDim.x + threadIdx.x) * 4;
    if (i + 3 < n) {
        float4 v = *(const float4*)(in + i);
        out[i + 0] = __float2bfloat16(v.x);
        out[i + 1] = __float2bfloat16(v.y);
        out[i + 2] = __float2bfloat16(v.z);
        out[i + 3] = __float2bfloat16(v.w);
    }
}

// in: [R,S] fp32 -> out: [S,R] bf16 (batched over z)
__global__ void k_transpose(const float* __restrict__ in, bf16* __restrict__ out,
                            int R, int S) {
    __shared__ float tile[32][33];
    size_t mat = (size_t)blockIdx.z * R * S;
    int s0 = blockIdx.x * 32, r0 = blockIdx.y * 32;
    int tx = threadIdx.x, ty = threadIdx.y;
    #pragma unroll
    for (int i = 0; i < 32; i += 8)
        tile[ty + i][tx] = in[mat + (size_t)(r0 + ty + i) * S + s0 + tx];
    __syncthreads();
    #pragma unroll
    for (int i = 0; i < 32; i += 8)
        out[mat + (size_t)(s0 + ty + i) * R + r0 + tx] = __float2bfloat16(tile[tx][ty + i]);
}

// gate: fp32 logits, sigmoid, top-4, normalize, build expert lists
__global__ void k_gate(const float* __restrict__ x, const float* __restrict__ wg,
                       const float* __restrict__ bias, int* __restrict__ cnt,
                       int* __restrict__ tok, float* __restrict__ wl) {
    __shared__ float gates[16][17];
    int t = threadIdx.x;
    int tl = t >> 4;
    int e = t & 15;
    int token = blockIdx.x * 16 + tl;
    const float* xr = x + (size_t)token * 768;
    float acc = 0.f;
    #pragma unroll 4
    for (int c = 0; c < 768; ++c) acc += xr[c] * wg[c * 16 + e];
    acc += bias[e];
    gates[tl][e] = 1.f / (1.f + expf(-acc));
    __syncthreads();
    if (t < 16) {
        int token2 = blockIdx.x * 16 + t;
        float g[16];
        #pragma unroll
        for (int j = 0; j < 16; ++j) g[j] = gates[t][j];
        int idx[4]; float w[4]; float sum = 0.f;
        #pragma unroll
        for (int k = 0; k < 4; ++k) {
            float best = -1e30f; int bi = 0;
            #pragma unroll
            for (int j = 0; j < 16; ++j)
                if (g[j] > best) { best = g[j]; bi = j; }
            idx[k] = bi; w[k] = best; sum += best; g[bi] = -1e30f;
        }
        float inv = 1.f / sum;
        for (int k = 0; k < 4; ++k) {
            int slot = atomicAdd(&cnt[idx[k]], 1);
            tok[(idx[k] << 13) + slot] = token2;
            wl[(idx[k] << 13) + slot] = w[k] * inv;
        }
    }
}

__global__ void k_offsets(const int* __restrict__ cnt, int* __restrict__ offs) {
    if (threadIdx.x == 0) {
        int s = 0;
        for (int e = 0; e < 16; ++e) { offs[e] = s; s += cnt[e]; }
    }
}

// ---------------- FC GEMM with fused SwiGLU ----------------
// A [*,768] bf16, BT [(E*)6144,768] bf16 (row n = fc col n), act [*,3072] bf16
// Block computes 128 rows x 64 act-cols: needs gate tile (BT rows n0..n0+63)
// and val tile (BT rows 3072+n0..). 4 waves: wm=w&1 (row half), wn=w>>1 (col half).
template<int GATHER>
__global__ __launch_bounds__(256) void k_fc_swiglu(
    const bf16* __restrict__ A, const bf16* __restrict__ BT,
    bf16* __restrict__ act, const int* __restrict__ cnt,
    const int* __restrict__ offs, const int* __restrict__ tok) {
    const int Kd = 768, H = 3072;
    int e = blockIdx.z;
    int m0 = blockIdx.y * BM;
    int n0 = blockIdx.x * 64;
    int M;
    size_t actbase = 0;
    const int* tl = nullptr;
    if (GATHER) {
        M = cnt[e];
        if (m0 >= M) return;
        tl = tok + (e << 13);
        actbase = (size_t)offs[e] * H;
        BT += (size_t)e * 6144 * Kd;
    } else {
        M = 8192;
    }

    __shared__ bf16 sA[BM * BK];   // 8 KB, row-major [128][32]
    __shared__ bf16 sBg[64 * BK];  // 4 KB
    __shared__ bf16 sBv[64 * BK];  // 4 KB

    int tid = threadIdx.x;
    int lane = tid & 63;
    int w = tid >> 6;
    int wm = w & 1, wn = w >> 1;

    // staging chunks: chunk c -> row c/4, k-subchunk (c&3)*8, LDS byte offset c*16
    int cA0 = (w << 6) + lane;        // A rows 0..63
    int cA1 = 256 + cA0;              // A rows 64..127
    int cB = (w << 6) + lane;         // B rows 0..63

    int rA0 = cA0 >> 2, rA1 = cA1 >> 2, rB = cB >> 2;
    int kA0 = (cA0 & 3) * 8, kA1 = (cA1 & 3) * 8, kB = (cB & 3) * 8;

    int grA0, grA1;
    if (GATHER) {
        grA0 = tl[min(m0 + rA0, M - 1)];
        grA1 = tl[min(m0 + rA1, M - 1)];
    } else {
        grA0 = m0 + rA0; grA1 = m0 + rA1;
    }

    const bf16* gA0 = A + (size_t)grA0 * Kd + kA0;
    const bf16* gA1 = A + (size_t)grA1 * Kd + kA1;
    const bf16* gBg = BT + (size_t)(n0 + rB) * Kd + kB;
    const bf16* gBv = BT + (size_t)(H + n0 + rB) * Kd + kB;
    bf16* sA0p = sA + cA0 * 8;
    bf16* sA1p = sA + cA1 * 8;
    bf16* sBgp = sBg + cB * 8;
    bf16* sBvp = sBv + cB * 8;

    float4v ag[4][2] = {};
    float4v av[4][2] = {};
    int quad = lane >> 4, l16 = lane & 15;

    for (int k0 = 0; k0 < Kd; k0 += BK) {
        __syncthreads();
        gload16(gA0 + k0, sA0p);
        gload16(gA1 + k0, sA1p);
        gload16(gBg + k0, sBgp);
        gload16(gBv + k0, sBvp);
        __syncthreads();
        short8 af[4], bg[2], bv[2];
        #pragma unroll
        for (int mf = 0; mf < 4; ++mf)
            af[mf] = *(const short8*)(sA + ((wm * 64 + mf * 16 + l16) * BK + quad * 8));
        #pragma unroll
        for (int nf = 0; nf < 2; ++nf) {
            bg[nf] = *(const short8*)(sBg + ((wn * 32 + nf * 16 + l16) * BK + quad * 8));
            bv[nf] = *(const short8*)(sBv + ((wn * 32 + nf * 16 + l16) * BK + quad * 8));
        }
        #pragma unroll
        for (int mf = 0; mf < 4; ++mf)
            #pragma unroll
            for (int nf = 0; nf < 2; ++nf) {
                ag[mf][nf] = __builtin_amdgcn_mfma_f32_16x16x32_bf16(af[mf], bg[nf], ag[mf][nf], 0, 0, 0);
                av[mf][nf] = __builtin_amdgcn_mfma_f32_16x16x32_bf16(af[mf], bv[nf], av[mf][nf], 0, 0, 0);
            }
    }

    #pragma unroll
    for (int mf = 0; mf < 4; ++mf)
        #pragma unroll
        for (int nf = 0; nf < 2; ++nf)
            #pragma unroll
            for (int r = 0; r < 4; ++r) {
                int mrow = m0 + wm * 64 + mf * 16 + quad * 4 + r;
                if (GATHER && mrow >= M) continue;
                int col = n0 + wn * 32 + nf * 16 + l16;
                float g = ag[mf][nf][r];
                float v = av[mf][nf][r];
                float sg = g / (1.f + __expf(-g));
                act[actbase + (size_t)mrow * H + col] = __float2bfloat16(sg * v);
            }
}

// ---------------- Proj GEMM ----------------
// A [*,3072] bf16, PT [(E*)768,3072] bf16, out [8192,768] fp32
template<int ROUTED>
__global__ __launch_bounds__(256) void k_proj(
    const bf16* __restrict__ Aact, const bf16* __restrict__ PT,
    float* __restrict__ out, const int* __restrict__ cnt,
    const int* __restrict__ offs, const int* __restrict__ tok,
    const float* __restrict__ wl) {
    const int Kd = 3072;
    int e = blockIdx.z;
    int m0 = blockIdx.y * BM;
    int n0 = blockIdx.x * BM;
    int M;
    size_t abase = 0;
    if (ROUTED) {
        M = cnt[e];
        if (m0 >= M) return;
        abase = (size_t)offs[e] * Kd;
        PT += (size_t)e * 768 * Kd;
    } else {
        M = 8192;
    }

    __shared__ bf16 sA[BM * BK];
    __shared__ bf16 sB[BM * BK];

    int tid = threadIdx.x, lane = tid & 63, w = tid >> 6;
    int wm = w & 1, wn = w >> 1;
    int c0 = (w << 6) + lane;
    int c1 = 256 + c0;
    int r0 = c0 >> 2, r1 = c1 >> 2;
    int k0c = (c0 & 3) * 8, k1c = (c1 & 3) * 8;

    int ra0 = min(m0 + r0, M - 1);
    int ra1 = min(m0 + r1, M - 1);
    const bf16* gA0 = Aact + abase + (size_t)ra0 * Kd + k0c;
    const bf16* gA1 = Aact + abase + (size_t)ra1 * Kd + k1c;
    const bf16* gB0 = PT + (size_t)(n0 + r0) * Kd + k0c;
    const bf16* gB1 = PT + (size_t)(n0 + r1) * Kd + k1c;
    bf16* sA0p = sA + c0 * 8;
    bf16* sA1p = sA + c1 * 8;
    bf16* sB0p = sB + c0 * 8;
    bf16* sB1p = sB + c1 * 8;

    float4v acc[4][4] = {};
    int quad = lane >> 4, l16 = lane & 15;

    for (int kk = 0; kk < Kd; kk += BK) {
        __syncthreads();
        gload16(gA0 + kk, sA0p);
        gload16(gA1 + kk, sA1p);
        gload16(gB0 + kk, sB0p);
        gload16(gB1 + kk, sB1p);
        __syncthreads();
        short8 af[4], bb[4];
        #pragma unroll
        for (int i = 0; i < 4; ++i) {
            af[i] = *(const short8*)(sA + ((wm * 64 + i * 16 + l16) * BK + quad * 8));
            bb[i] = *(const short8*)(sB + ((wn * 64 + i * 16 + l16) * BK + quad * 8));
        }
        #pragma unroll
        for (int mf = 0; mf < 4; ++mf)
            #pragma unroll
            for (int nf = 0; nf < 4; ++nf)
                acc[mf][nf] = __builtin_amdgcn_mfma_f32_16x16x32_bf16(af[mf], bb[nf], acc[mf][nf], 0, 0, 0);
    }

    #pragma unroll
    for (int mf = 0; mf < 4; ++mf) {
        #pragma unroll
        for (int r = 0; r < 4; ++r) {
            int mr = m0 + wm * 64 + mf * 16 + quad * 4 + r;
            if (ROUTED) {
                if (mr < M) {
                    int t = tok[(e << 13) + mr];
                    float wgt = wl[(e << 13) + mr];
                    #pragma unroll
                    for (int nf = 0; nf < 4; ++nf) {
                        int col = n0 + wn * 64 + nf * 16 + l16;
                        atomicAdd(out + (size_t)t * 768 + col, wgt * acc[mf][nf][r]);
                    }
                }
            } else {
                #pragma unroll
                for (int nf = 0; nf < 4; ++nf) {
                    int col = n0 + wn * 64 + nf * 16 + l16;
                    out[(size_t)mr * 768 + col] = acc[mf][nf][r];
                }
            }
        }
    }
}

// ---------------- launch ----------------

extern "C" void kernel_launch(void* const* d_in, const int* in_sizes, int n_in,
                              void* d_out, int out_size, void* d_ws, size_t ws_size,
                              hipStream_t stream) {
    const float* x    = (const float*)d_in[0];
    const float* wfc  = (const float*)d_in[1];
    const float* wpr  = (const float*)d_in[2];
    const float* wefc = (const float*)d_in[3];
    const float* wepr = (const float*)d_in[4];
    const float* wg   = (const float*)d_in[5];
    const float* eb   = (const float*)d_in[6];
    float* out = (float*)d_out;

    char* p = (char*)d_ws;
    bf16* x_bf  = (bf16*)p; p += (size_t)8192 * 768 * 2;
    bf16* fcT_s = (bf16*)p; p += (size_t)6144 * 768 * 2;
    bf16* prT_s = (bf16*)p; p += (size_t)768 * 3072 * 2;
    bf16* fcT_e = (bf16*)p; p += (size_t)16 * 6144 * 768 * 2;
    bf16* prT_e = (bf16*)p; p += (size_t)16 * 768 * 3072 * 2;
    bf16* act_s = (bf16*)p; p += (size_t)8192 * 3072 * 2;
    bf16* act_r = (bf16*)p; p += (size_t)32768 * 3072 * 2;
    int* cnt    = (int*)p;  p += 64;
    int* offs   = (int*)p;  p += 64;
    int* tok    = (int*)p;  p += (size_t)16 * 8192 * 4;
    float* wl   = (float*)p; p += (size_t)16 * 8192 * 4;

    k_zero_cnt<<<dim3(1), dim3(64), 0, stream>>>(cnt);
    k_convert_x<<<dim3(6144), dim3(256), 0, stream>>>(x, x_bf, 8192 * 768);
    k_transpose<<<dim3(192, 24, 1), dim3(32, 8), 0, stream>>>(wfc, fcT_s, 768, 6144);
    k_transpose<<<dim3(24, 96, 1), dim3(32, 8), 0, stream>>>(wpr, prT_s, 3072, 768);
    k_transpose<<<dim3(192, 24, 16), dim3(32, 8), 0, stream>>>(wefc, fcT_e, 768, 6144);
    k_transpose<<<dim3(24, 96, 16), dim3(32, 8), 0, stream>>>(wepr, prT_e, 3072, 768);
    k_gate<<<dim3(512), dim3(256), 0, stream>>>(x, wg, eb, cnt, tok, wl);
    k_offsets<<<dim3(1), dim3(64), 0, stream>>>(cnt, offs);

    k_fc_swiglu<0><<<dim3(48, 64, 1), dim3(256), 0, stream>>>(x_bf, fcT_s, act_s, cnt, offs, tok);
    k_fc_swiglu<1><<<dim3(48, 64, 16), dim3(256), 0, stream>>>(x_bf, fcT_e, act_r, cnt, offs, tok);
    k_proj<0><<<dim3(6, 64, 1), dim3(256), 0, stream>>>(act_s, prT_s, out, cnt, offs, tok, wl);
    k_proj<1><<<dim3(6, 64, 16), dim3(256), 0, stream>>>(act_r, prT_e, out, cnt, offs, tok, wl);
}

// Round 2
// 1649.109 us; speedup vs baseline: 1.0678x; 1.0678x over previous
//
#include <hip/hip_runtime.h>
#include <hip/hip_bf16.h>

typedef __hip_bfloat16 bf16;
typedef __attribute__((ext_vector_type(8))) short short8;
typedef __attribute__((ext_vector_type(4))) float float4v;

#define BK 32

__device__ __forceinline__ void gload16(const bf16* g, bf16* s) {
    __builtin_amdgcn_global_load_lds(
        (const __attribute__((address_space(1))) void*)g,
        (__attribute__((address_space(3))) void*)s, 16, 0, 0);
}

// ---------------- small utility kernels ----------------

__global__ void k_zero_cnt(int* cnt) {
    if (threadIdx.x < 16) cnt[threadIdx.x] = 0;
}

__global__ void k_convert_x(const float* __restrict__ in, bf16* __restrict__ out, int n) {
    int i = (blockIdx.x * blockDim.x + threadIdx.x) * 4;
    if (i + 3 < n) {
        float4 v = *(const float4*)(in + i);
        out[i + 0] = __float2bfloat16(v.x);
        out[i + 1] = __float2bfloat16(v.y);
        out[i + 2] = __float2bfloat16(v.z);
        out[i + 3] = __float2bfloat16(v.w);
    }
}

// in: [R,S] fp32 -> out: [S,R] bf16 (batched over z)
__global__ void k_transpose(const float* __restrict__ in, bf16* __restrict__ out,
                            int R, int S) {
    __shared__ float tile[32][33];
    size_t mat = (size_t)blockIdx.z * R * S;
    int s0 = blockIdx.x * 32, r0 = blockIdx.y * 32;
    int tx = threadIdx.x, ty = threadIdx.y;
    #pragma unroll
    for (int i = 0; i < 32; i += 8)
        tile[ty + i][tx] = in[mat + (size_t)(r0 + ty + i) * S + s0 + tx];
    __syncthreads();
    #pragma unroll
    for (int i = 0; i < 32; i += 8)
        out[mat + (size_t)(s0 + ty + i) * R + r0 + tx] = __float2bfloat16(tile[tx][ty + i]);
}

// gate: fp32 logits, sigmoid, top-4, normalize, build expert lists
__global__ void k_gate(const float* __restrict__ x, const float* __restrict__ wg,
                       const float* __restrict__ bias, int* __restrict__ cnt,
                       int* __restrict__ tok, float* __restrict__ wl) {
    __shared__ float gates[16][17];
    int t = threadIdx.x;
    int tl = t >> 4;
    int e = t & 15;
    int token = blockIdx.x * 16 + tl;
    const float* xr = x + (size_t)token * 768;
    float acc = 0.f;
    #pragma unroll 4
    for (int c = 0; c < 768; ++c) acc += xr[c] * wg[c * 16 + e];
    acc += bias[e];
    gates[tl][e] = 1.f / (1.f + expf(-acc));
    __syncthreads();
    if (t < 16) {
        int token2 = blockIdx.x * 16 + t;
        float g[16];
        #pragma unroll
        for (int j = 0; j < 16; ++j) g[j] = gates[t][j];
        int idx[4]; float w[4]; float sum = 0.f;
        #pragma unroll
        for (int k = 0; k < 4; ++k) {
            float best = -1e30f; int bi = 0;
            #pragma unroll
            for (int j = 0; j < 16; ++j)
                if (g[j] > best) { best = g[j]; bi = j; }
            idx[k] = bi; w[k] = best; sum += best; g[bi] = -1e30f;
        }
        float inv = 1.f / sum;
        for (int k = 0; k < 4; ++k) {
            int slot = atomicAdd(&cnt[idx[k]], 1);
            tok[(idx[k] << 13) + slot] = token2;
            wl[(idx[k] << 13) + slot] = w[k] * inv;
        }
    }
}

__global__ void k_offsets(const int* __restrict__ cnt, int* __restrict__ offs) {
    if (threadIdx.x == 0) {
        int s = 0;
        for (int e = 0; e < 16; ++e) { offs[e] = s; s += cnt[e]; }
    }
}

// ---------------- FC GEMM with fused SwiGLU ----------------
// A [*,768] bf16, BT [(E*)6144,768] bf16, act [*,3072] bf16.
// Tile: 128 rows x 128 act cols (stages gate rows n0..n0+127 and val rows
// 3072+n0..+127). 512 threads = 8 waves; wave w: wm=w&1 (64-row half),
// wn=w>>1 (32-col quarter). 16 MFMA / wave / K-step, 3 gload16 / thread.
// LDS XOR swizzle: chunk (row r, k2) stored at slot r*4 + (k2 ^ ((r>>1)&3))
// -> 16-lane ds_read_b128 groups spread over 8 bank-quads (2-way = free).
template<int GATHER>
__global__ __launch_bounds__(512) void k_fc_swiglu(
    const bf16* __restrict__ A, const bf16* __restrict__ BT,
    bf16* __restrict__ act, const int* __restrict__ cnt,
    const int* __restrict__ offs, const int* __restrict__ tok) {
    const int Kd = 768, H = 3072;
    int e = blockIdx.z;
    int m0 = blockIdx.y * 128;
    int n0 = blockIdx.x * 128;
    int M;
    size_t actbase = 0;
    const int* tl = nullptr;
    if (GATHER) {
        M = cnt[e];
        if (m0 >= M) return;
        tl = tok + (e << 13);
        actbase = (size_t)offs[e] * H;
        BT += (size_t)e * 6144 * Kd;
    } else {
        M = 8192;
    }

    __shared__ bf16 sA[128 * BK];   // 8 KB
    __shared__ bf16 sBg[128 * BK];  // 8 KB
    __shared__ bf16 sBv[128 * BK];  // 8 KB

    int tid = threadIdx.x;
    int lane = tid & 63;
    int w = tid >> 6;
    int wm = w & 1, wn = w >> 1;   // wn in 0..3

    // staging: slot s = tid in each buffer; inverse swizzle for global k-chunk
    int sr = tid >> 2;                       // row 0..127
    int k2 = (tid & 3) ^ ((sr >> 1) & 3);    // actual k-subchunk

    int grA = GATHER ? tl[min(m0 + sr, M - 1)] : (m0 + sr);
    const bf16* gA  = A  + (size_t)grA * Kd + k2 * 8;
    const bf16* gBg = BT + (size_t)(n0 + sr) * Kd + k2 * 8;
    const bf16* gBv = BT + (size_t)(H + n0 + sr) * Kd + k2 * 8;
    bf16* sAp  = sA  + tid * 8;
    bf16* sBgp = sBg + tid * 8;
    bf16* sBvp = sBv + tid * 8;

    float4v ag[4][2] = {};
    float4v av[4][2] = {};
    int quad = lane >> 4, l16 = lane & 15;
    int q2 = quad ^ ((l16 >> 1) & 3);        // swizzled read quad (row base %16==0)

    for (int k0 = 0; k0 < Kd; k0 += BK) {
        __syncthreads();
        gload16(gA + k0, sAp);
        gload16(gBg + k0, sBgp);
        gload16(gBv + k0, sBvp);
        __syncthreads();
        short8 af[4], bg[2], bv[2];
        #pragma unroll
        for (int mf = 0; mf < 4; ++mf) {
            int row = wm * 64 + mf * 16 + l16;
            af[mf] = *(const short8*)(sA + row * BK + q2 * 8);
        }
        #pragma unroll
        for (int nf = 0; nf < 2; ++nf) {
            int row = wn * 32 + nf * 16 + l16;
            bg[nf] = *(const short8*)(sBg + row * BK + q2 * 8);
            bv[nf] = *(const short8*)(sBv + row * BK + q2 * 8);
        }
        #pragma unroll
        for (int mf = 0; mf < 4; ++mf)
            #pragma unroll
            for (int nf = 0; nf < 2; ++nf) {
                ag[mf][nf] = __builtin_amdgcn_mfma_f32_16x16x32_bf16(af[mf], bg[nf], ag[mf][nf], 0, 0, 0);
                av[mf][nf] = __builtin_amdgcn_mfma_f32_16x16x32_bf16(af[mf], bv[nf], av[mf][nf], 0, 0, 0);
            }
    }

    #pragma unroll
    for (int mf = 0; mf < 4; ++mf)
        #pragma unroll
        for (int nf = 0; nf < 2; ++nf)
            #pragma unroll
            for (int r = 0; r < 4; ++r) {
                int mrow = m0 + wm * 64 + mf * 16 + quad * 4 + r;
                if (GATHER && mrow >= M) continue;
                int col = n0 + wn * 32 + nf * 16 + l16;
                float g = ag[mf][nf][r];
                float v = av[mf][nf][r];
                float sg = g / (1.f + __expf(-g));
                act[actbase + (size_t)mrow * H + col] = __float2bfloat16(sg * v);
            }
}

// ---------------- Proj GEMM ----------------
// A [*,3072] bf16, PT [(E*)768,3072] bf16, out [8192,768] fp32.
// Tile 256 rows x 128 cols, 512 threads = 8 waves; wm=w&3, wn=w>>2.
// 16 MFMA / wave / K-step, 3 gload16 / thread. Same XOR swizzle.
template<int ROUTED>
__global__ __launch_bounds__(512) void k_proj(
    const bf16* __restrict__ Aact, const bf16* __restrict__ PT,
    float* __restrict__ out, const int* __restrict__ cnt,
    const int* __restrict__ offs, const int* __restrict__ tok,
    const float* __restrict__ wl) {
    const int Kd = 3072;
    int e = blockIdx.z;
    int m0 = blockIdx.y * 256;
    int n0 = blockIdx.x * 128;
    int M;
    size_t abase = 0;
    if (ROUTED) {
        M = cnt[e];
        if (m0 >= M) return;
        abase = (size_t)offs[e] * Kd;
        PT += (size_t)e * 768 * Kd;
    } else {
        M = 8192;
    }

    __shared__ bf16 sA[256 * BK];  // 16 KB
    __shared__ bf16 sB[128 * BK];  // 8 KB

    int tid = threadIdx.x, lane = tid & 63, w = tid >> 6;
    int wm = w & 3, wn = w >> 2;

    // staging: sA slots tid and tid+512, sB slot tid
    int srA0 = tid >> 2;
    int srA1 = (tid + 512) >> 2;
    int k2A0 = (tid & 3) ^ ((srA0 >> 1) & 3);
    int k2A1 = (tid & 3) ^ ((srA1 >> 1) & 3);
    int srB = tid >> 2;
    int k2B = (tid & 3) ^ ((srB >> 1) & 3);

    int ra0 = min(m0 + srA0, M - 1);
    int ra1 = min(m0 + srA1, M - 1);
    const bf16* gA0 = Aact + abase + (size_t)ra0 * Kd + k2A0 * 8;
    const bf16* gA1 = Aact + abase + (size_t)ra1 * Kd + k2A1 * 8;
    const bf16* gB  = PT + (size_t)(n0 + srB) * Kd + k2B * 8;
    bf16* sA0p = sA + tid * 8;
    bf16* sA1p = sA + (tid + 512) * 8;
    bf16* sBp  = sB + tid * 8;

    float4v acc[4][4] = {};
    int quad = lane >> 4, l16 = lane & 15;
    int q2 = quad ^ ((l16 >> 1) & 3);

    for (int kk = 0; kk < Kd; kk += BK) {
        __syncthreads();
        gload16(gA0 + kk, sA0p);
        gload16(gA1 + kk, sA1p);
        gload16(gB + kk, sBp);
        __syncthreads();
        short8 af[4], bb[4];
        #pragma unroll
        for (int i = 0; i < 4; ++i) {
            int rowa = wm * 64 + i * 16 + l16;
            int rowb = wn * 64 + i * 16 + l16;
            af[i] = *(const short8*)(sA + rowa * BK + q2 * 8);
            bb[i] = *(const short8*)(sB + rowb * BK + q2 * 8);
        }
        #pragma unroll
        for (int mf = 0; mf < 4; ++mf)
            #pragma unroll
            for (int nf = 0; nf < 4; ++nf)
                acc[mf][nf] = __builtin_amdgcn_mfma_f32_16x16x32_bf16(af[mf], bb[nf], acc[mf][nf], 0, 0, 0);
    }

    #pragma unroll
    for (int mf = 0; mf < 4; ++mf) {
        #pragma unroll
        for (int r = 0; r < 4; ++r) {
            int mr = m0 + wm * 64 + mf * 16 + quad * 4 + r;
            if (ROUTED) {
                if (mr < M) {
                    int t = tok[(e << 13) + mr];
                    float wgt = wl[(e << 13) + mr];
                    #pragma unroll
                    for (int nf = 0; nf < 4; ++nf) {
                        int col = n0 + wn * 64 + nf * 16 + l16;
                        atomicAdd(out + (size_t)t * 768 + col, wgt * acc[mf][nf][r]);
                    }
                }
            } else {
                #pragma unroll
                for (int nf = 0; nf < 4; ++nf) {
                    int col = n0 + wn * 64 + nf * 16 + l16;
                    out[(size_t)mr * 768 + col] = acc[mf][nf][r];
                }
            }
        }
    }
}

// ---------------- launch ----------------

extern "C" void kernel_launch(void* const* d_in, const int* in_sizes, int n_in,
                              void* d_out, int out_size, void* d_ws, size_t ws_size,
                              hipStream_t stream) {
    const float* x    = (const float*)d_in[0];
    const float* wfc  = (const float*)d_in[1];
    const float* wpr  = (const float*)d_in[2];
    const float* wefc = (const float*)d_in[3];
    const float* wepr = (const float*)d_in[4];
    const float* wg   = (const float*)d_in[5];
    const float* eb   = (const float*)d_in[6];
    float* out = (float*)d_out;

    char* p = (char*)d_ws;
    bf16* x_bf  = (bf16*)p; p += (size_t)8192 * 768 * 2;
    bf16* fcT_s = (bf16*)p; p += (size_t)6144 * 768 * 2;
    bf16* prT_s = (bf16*)p; p += (size_t)768 * 3072 * 2;
    bf16* fcT_e = (bf16*)p; p += (size_t)16 * 6144 * 768 * 2;
    bf16* prT_e = (bf16*)p; p += (size_t)16 * 768 * 3072 * 2;
    bf16* act_s = (bf16*)p; p += (size_t)8192 * 3072 * 2;
    bf16* act_r = (bf16*)p; p += (size_t)32768 * 3072 * 2;
    int* cnt    = (int*)p;  p += 64;
    int* offs   = (int*)p;  p += 64;
    int* tok    = (int*)p;  p += (size_t)16 * 8192 * 4;
    float* wl   = (float*)p; p += (size_t)16 * 8192 * 4;

    k_zero_cnt<<<dim3(1), dim3(64), 0, stream>>>(cnt);
    k_convert_x<<<dim3(6144), dim3(256), 0, stream>>>(x, x_bf, 8192 * 768);
    k_transpose<<<dim3(192, 24, 1), dim3(32, 8), 0, stream>>>(wfc, fcT_s, 768, 6144);
    k_transpose<<<dim3(24, 96, 1), dim3(32, 8), 0, stream>>>(wpr, prT_s, 3072, 768);
    k_transpose<<<dim3(192, 24, 16), dim3(32, 8), 0, stream>>>(wefc, fcT_e, 768, 6144);
    k_transpose<<<dim3(24, 96, 16), dim3(32, 8), 0, stream>>>(wepr, prT_e, 3072, 768);
    k_gate<<<dim3(512), dim3(256), 0, stream>>>(x, wg, eb, cnt, tok, wl);
    k_offsets<<<dim3(1), dim3(64), 0, stream>>>(cnt, offs);

    k_fc_swiglu<0><<<dim3(24, 64, 1), dim3(512), 0, stream>>>(x_bf, fcT_s, act_s, cnt, offs, tok);
    k_fc_swiglu<1><<<dim3(24, 64, 16), dim3(512), 0, stream>>>(x_bf, fcT_e, act_r, cnt, offs, tok);
    k_proj<0><<<dim3(6, 32, 1), dim3(512), 0, stream>>>(act_s, prT_s, out, cnt, offs, tok, wl);
    k_proj<1><<<dim3(6, 32, 16), dim3(512), 0, stream>>>(act_r, prT_e, out, cnt, offs, tok, wl);
}